// Round 10
// baseline (63.869 us; speedup 1.0000x reference)
//
#include <hip/hip_runtime.h>
#include <math.h>

#define NSLOT 5
#define EPSF 1e-8f

typedef float f4 __attribute__((ext_vector_type(4)));

static __device__ __forceinline__ float d4(f4 a, f4 b) {
    return fmaf(a.x, b.x, fmaf(a.y, b.y, fmaf(a.z, b.z, a.w * b.w)));
}

// ---------------- binning kernels ----------------

__global__ void hist_kernel(const int* __restrict__ labels, int* __restrict__ counts, int B) {
    int i = blockIdx.x * blockDim.x + threadIdx.x;
    if (i < B) atomicAdd(&counts[labels[i]], 1);
}

__global__ void scan_kernel(const int* __restrict__ counts, int* __restrict__ offsets,
                            int* __restrict__ cursor, int C) {
    __shared__ int sh[1024];
    __shared__ int running;
    if (threadIdx.x == 0) running = 0;
    __syncthreads();
    for (int base = 0; base < C; base += 1024) {
        int t = base + threadIdx.x;
        int v = (t < C) ? counts[t] : 0;
        sh[threadIdx.x] = v;
        __syncthreads();
        for (int d = 1; d < 1024; d <<= 1) {
            int x = (threadIdx.x >= d) ? sh[threadIdx.x - d] : 0;
            __syncthreads();
            sh[threadIdx.x] += x;
            __syncthreads();
        }
        int excl = sh[threadIdx.x] - v + running;
        if (t < C) { offsets[t] = excl; cursor[t] = excl; }
        __syncthreads();
        if (threadIdx.x == 0) running += sh[1023];
        __syncthreads();
    }
}

__global__ void scatter_kernel(const int* __restrict__ labels, int* __restrict__ cursor,
                               int* __restrict__ bucket, int B) {
    int i = blockIdx.x * blockDim.x + threadIdx.x;
    if (i < B) {
        int slot = atomicAdd(&cursor[labels[i]], 1);
        bucket[slot] = i;
    }
}

// ---------------- class-centric main kernel (D=2048) ----------------
// One block per class. Keys staged in LDS ONCE (kills the 5x key re-read
// through L1). 256 threads cooperate on ONE sample at a time, 2 f4-chunks
// per thread (no per-thread register arrays -> no scratch, R6's failure).
// Key norms computed once per class. Next sample's q prefetched during
// the current sample's compute.

__global__ __launch_bounds__(256, 3) void mb_class_kernel(
    const float* __restrict__ query,
    const float* __restrict__ mkeys,
    const float* __restrict__ mvals,
    const float* __restrict__ qscores,
    const int*   __restrict__ topk_p,
    const int*   __restrict__ counts,
    const int*   __restrict__ offsets,
    const int*   __restrict__ bucket,
    float* __restrict__ out_ret,
    float* __restrict__ out_w)
{
    const int c   = blockIdx.x;
    const int cnt = counts[c];
    if (cnt == 0) return;
    const int off  = offsets[c];
    const int tid  = threadIdx.x;
    const int lane = tid & 63;
    const int wave = tid >> 6;

    __shared__ f4    kls[NSLOT * 512];   // 40 KiB: class's 5 key rows
    __shared__ float red[4][8];          // per-wave partials

    const f4* kc    = reinterpret_cast<const f4*>(mkeys) + (size_t)c * NSLOT * 512;
    const f4* vc    = reinterpret_cast<const f4*>(mvals) + (size_t)c * NSLOT * 512;
    const f4* qbase = reinterpret_cast<const f4*>(query);

    // prefetch first sample's q (completes under key staging)
    int i_cur = bucket[off];
    f4 qa = qbase[(size_t)i_cur * 512 + tid];
    f4 qb = qbase[(size_t)i_cur * 512 + tid + 256];

    // stage keys: 10 f4-loads per thread, contiguous
#pragma unroll
    for (int m = 0; m < 2 * NSLOT; ++m)
        kls[tid + m * 256] = kc[tid + m * 256];

    int k = topk_p[0];
    if (k > NSLOT) k = NSLOT;
    if (k < 1) k = 1;

    float scr[NSLOT];
    float ssum = 0.f;
#pragma unroll
    for (int s = 0; s < NSLOT; ++s) {
        scr[s] = qscores[(size_t)c * NSLOT + s];
        ssum += scr[s];
    }
    const bool hit = (ssum != 0.0f);

    __syncthreads();

    // ---- per-class key norms (once) ----
    float kkp[NSLOT];
#pragma unroll
    for (int s = 0; s < NSLOT; ++s) {
        f4 k0 = kls[s * 512 + tid];
        f4 k1 = kls[s * 512 + tid + 256];
        kkp[s] = d4(k0, k0) + d4(k1, k1);
    }
#pragma unroll
    for (int o = 1; o < 64; o <<= 1) {
#pragma unroll
        for (int s = 0; s < NSLOT; ++s) kkp[s] += __shfl_xor(kkp[s], o);
    }
    if (lane == 0) {
#pragma unroll
        for (int s = 0; s < NSLOT; ++s) red[wave][s] = kkp[s];
    }
    __syncthreads();
    float fac[NSLOT];   // scr[s]/kn[s]; comb = (dot/qn)*fac (same algebra as ref)
#pragma unroll
    for (int s = 0; s < NSLOT; ++s) {
        float kkt = red[0][s] + red[1][s] + red[2][s] + red[3][s];
        fac[s] = scr[s] / fmaxf(sqrtf(kkt), EPSF);
    }
    __syncthreads();

    // ---- samples of this class, serially; q prefetched one ahead ----
    for (int j = 0; j < cnt; ++j) {
        const int i_next = (j + 1 < cnt) ? bucket[off + j + 1] : i_cur;
        f4 qa_n = qbase[(size_t)i_next * 512 + tid];
        f4 qb_n = qbase[(size_t)i_next * 512 + tid + 256];

        // partial qq + dots against LDS keys
        float qqp = d4(qa, qa) + d4(qb, qb);
        float dp[NSLOT];
#pragma unroll
        for (int s = 0; s < NSLOT; ++s)
            dp[s] = d4(qa, kls[s * 512 + tid]) + d4(qb, kls[s * 512 + tid + 256]);

#pragma unroll
        for (int o = 1; o < 64; o <<= 1) {
            qqp += __shfl_xor(qqp, o);
#pragma unroll
            for (int s = 0; s < NSLOT; ++s) dp[s] += __shfl_xor(dp[s], o);
        }
        if (lane == 0) {
            red[wave][5] = qqp;
#pragma unroll
            for (int s = 0; s < NSLOT; ++s) red[wave][s] = dp[s];
        }
        __syncthreads();
        float qq = red[0][5] + red[1][5] + red[2][5] + red[3][5];
        float dot[NSLOT];
#pragma unroll
        for (int s = 0; s < NSLOT; ++s)
            dot[s] = red[0][s] + red[1][s] + red[2][s] + red[3][s];
        __syncthreads();   // red reusable next iteration

        // ---- epilogue (redundant on all 256 threads) ----
        float qn = fmaxf(sqrtf(qq), EPSF);
        float comb[NSLOT];
#pragma unroll
        for (int s = 0; s < NSLOT; ++s) comb[s] = (dot[s] / qn) * fac[s];

        bool used[NSLOT];
#pragma unroll
        for (int s = 0; s < NSLOT; ++s) used[s] = false;
        float tsc[NSLOT];
        int   tix[NSLOT];
#pragma unroll
        for (int jj = 0; jj < NSLOT; ++jj) {
            float best = -INFINITY;
            int bi = 0;
            if (jj < k) {
#pragma unroll
                for (int s = 0; s < NSLOT; ++s) {
                    if (!used[s] && comb[s] > best) { best = comb[s]; bi = s; }
                }
#pragma unroll
                for (int s = 0; s < NSLOT; ++s) used[s] = used[s] || (s == bi);
            }
            tsc[jj] = best;
            tix[jj] = bi;
        }

        float m0 = tsc[0];
        float esum = 0.f, wsum = 0.f;
        float a[NSLOT];
#pragma unroll
        for (int jj = 0; jj < NSLOT; ++jj) {
            if (jj < k) {
                a[jj] = __expf((tsc[jj] - m0) * 10.0f);   // 1/TEMP = 10
                esum += a[jj];
                wsum += tsc[jj];
            } else {
                a[jj] = 0.f;
            }
        }
        float inv = hit ? (1.0f / esum) : 0.0f;

        if (tid == 0) out_w[i_cur] = hit ? (wsum / (float)k) : 0.0f;

        // ---- pass 2: selected value rows only (block-uniform rows) ----
        f4* o4 = reinterpret_cast<f4*>(out_ret) + (size_t)i_cur * 512;
        if (k == 3) {
            const float a0 = a[0] * inv, a1 = a[1] * inv, a2 = a[2] * inv;
            const f4* p0 = vc + tix[0] * 512;
            const f4* p1 = vc + tix[1] * 512;
            const f4* p2 = vc + tix[2] * 512;
            f4 v00 = p0[tid], v01 = p0[tid + 256];
            f4 v10 = p1[tid], v11 = p1[tid + 256];
            f4 v20 = p2[tid], v21 = p2[tid + 256];
            f4 acc0, acc1;
            acc0.x = fmaf(a0, v00.x, fmaf(a1, v10.x, a2 * v20.x));
            acc0.y = fmaf(a0, v00.y, fmaf(a1, v10.y, a2 * v20.y));
            acc0.z = fmaf(a0, v00.z, fmaf(a1, v10.z, a2 * v20.z));
            acc0.w = fmaf(a0, v00.w, fmaf(a1, v10.w, a2 * v20.w));
            acc1.x = fmaf(a0, v01.x, fmaf(a1, v11.x, a2 * v21.x));
            acc1.y = fmaf(a0, v01.y, fmaf(a1, v11.y, a2 * v21.y));
            acc1.z = fmaf(a0, v01.z, fmaf(a1, v11.z, a2 * v21.z));
            acc1.w = fmaf(a0, v01.w, fmaf(a1, v11.w, a2 * v21.w));
            o4[tid] = acc0;
            o4[tid + 256] = acc1;
        } else {
            float wgt[NSLOT];
#pragma unroll
            for (int s = 0; s < NSLOT; ++s) {
                float wsv = 0.f;
#pragma unroll
                for (int jj = 0; jj < NSLOT; ++jj)
                    if (jj < k && tix[jj] == s) wsv += a[jj] * inv;
                wgt[s] = wsv;
            }
            f4 acc0 = (f4)(0.f), acc1 = (f4)(0.f);
#pragma unroll
            for (int s = 0; s < NSLOT; ++s) {
                f4 v0 = vc[s * 512 + tid];
                f4 v1 = vc[s * 512 + tid + 256];
                acc0.x = fmaf(wgt[s], v0.x, acc0.x);
                acc0.y = fmaf(wgt[s], v0.y, acc0.y);
                acc0.z = fmaf(wgt[s], v0.z, acc0.z);
                acc0.w = fmaf(wgt[s], v0.w, acc0.w);
                acc1.x = fmaf(wgt[s], v1.x, acc1.x);
                acc1.y = fmaf(wgt[s], v1.y, acc1.y);
                acc1.z = fmaf(wgt[s], v1.z, acc1.z);
                acc1.w = fmaf(wgt[s], v1.w, acc1.w);
            }
            o4[tid] = acc0;
            o4[tid + 256] = acc1;
        }

        qa = qa_n;
        qb = qb_n;
        i_cur = i_next;
    }
}

// ---------------- generic fallback (any D), sample-centric ----------------

__global__ __launch_bounds__(64) void mb_generic_kernel(
    const float* __restrict__ query,
    const int*   __restrict__ labels,
    const float* __restrict__ mkeys,
    const float* __restrict__ mvals,
    const float* __restrict__ qscores,
    const int*   __restrict__ topk_p,
    float* __restrict__ out_ret,
    float* __restrict__ out_w,
    int B, int n4)
{
    const int lane = threadIdx.x;
    const int i    = blockIdx.x;
    if (i >= B) return;
    const int c = labels[i];
    int k = topk_p[0];
    if (k > NSLOT) k = NSLOT;
    if (k < 1) k = 1;

    const f4* q4 = reinterpret_cast<const f4*>(query) + (size_t)i * n4;
    const f4* k4 = reinterpret_cast<const f4*>(mkeys) + (size_t)c * NSLOT * n4;
    const f4* v4 = reinterpret_cast<const f4*>(mvals) + (size_t)c * NSLOT * n4;
    f4*       o4 = reinterpret_cast<f4*>(out_ret) + (size_t)i * n4;

    float qq = 0.f, dot[NSLOT] = {0}, kk[NSLOT] = {0};
    for (int idx = lane; idx < n4; idx += 64) {
        f4 q = q4[idx];
        qq += d4(q, q);
        for (int s = 0; s < NSLOT; ++s) {
            f4 t = k4[s * n4 + idx];
            dot[s] += d4(q, t);
            kk[s]  += d4(t, t);
        }
    }
    for (int o = 1; o < 64; o <<= 1) {
        qq += __shfl_xor(qq, o);
        for (int s = 0; s < NSLOT; ++s) {
            dot[s] += __shfl_xor(dot[s], o);
            kk[s]  += __shfl_xor(kk[s], o);
        }
    }
    float qn = fmaxf(sqrtf(qq), EPSF);
    float scr[NSLOT], ssum = 0.f;
    for (int s = 0; s < NSLOT; ++s) { scr[s] = qscores[(size_t)c * NSLOT + s]; ssum += scr[s]; }
    float comb[NSLOT];
    for (int s = 0; s < NSLOT; ++s)
        comb[s] = (dot[s] / (qn * fmaxf(sqrtf(kk[s]), EPSF))) * scr[s];
    bool used[NSLOT] = {false, false, false, false, false};
    float tsc[NSLOT]; int tix[NSLOT];
    for (int jj = 0; jj < NSLOT; ++jj) {
        float best = -INFINITY; int bi = 0;
        if (jj < k) {
            for (int s = 0; s < NSLOT; ++s)
                if (!used[s] && comb[s] > best) { best = comb[s]; bi = s; }
            used[bi] = true;
        }
        tsc[jj] = best; tix[jj] = bi;
    }
    const bool hit = (ssum != 0.0f);
    float m = tsc[0], esum = 0.f, wsum = 0.f, a[NSLOT];
    for (int jj = 0; jj < NSLOT; ++jj) {
        if (jj < k) { a[jj] = __expf((tsc[jj] - m) * 10.0f); esum += a[jj]; wsum += tsc[jj]; }
        else a[jj] = 0.f;
    }
    float inv = hit ? (1.0f / esum) : 0.0f;
    float w[NSLOT];
    for (int s = 0; s < NSLOT; ++s) {
        float wsv = 0.f;
        for (int jj = 0; jj < NSLOT; ++jj) if (jj < k && tix[jj] == s) wsv += a[jj] * inv;
        w[s] = wsv;
    }
    if (lane == 0) out_w[i] = hit ? (wsum / (float)k) : 0.0f;
    for (int idx = lane; idx < n4; idx += 64) {
        f4 acc = (f4)(0.f);
        for (int s = 0; s < NSLOT; ++s) {
            f4 v = v4[s * n4 + idx];
            acc += v * w[s];
        }
        o4[idx] = acc;
    }
}

extern "C" void kernel_launch(void* const* d_in, const int* in_sizes, int n_in,
                              void* d_out, int out_size, void* d_ws, size_t ws_size,
                              hipStream_t stream) {
    const float* query   = (const float*)d_in[0];
    const int*   labels  = (const int*)d_in[1];
    const float* mkeys   = (const float*)d_in[2];
    const float* mvals   = (const float*)d_in[3];
    const float* qscores = (const float*)d_in[4];
    const int*   topk    = (const int*)d_in[5];

    const int B  = in_sizes[1];
    const int D  = in_sizes[0] / B;
    const int n4 = D >> 2;
    const int C  = in_sizes[4] / NSLOT;

    float* out_ret = (float*)d_out;
    float* out_w   = out_ret + (size_t)B * D;

    if (D == 2048 && ((size_t)(3 * C + B) * sizeof(int) <= ws_size)) {
        int* counts  = (int*)d_ws;
        int* offsets = counts + C;
        int* cursor  = offsets + C;
        int* bkt     = cursor + C;
        hipMemsetAsync(counts, 0, (size_t)C * sizeof(int), stream);
        hist_kernel<<<dim3((B + 255) / 256), dim3(256), 0, stream>>>(labels, counts, B);
        scan_kernel<<<dim3(1), dim3(1024), 0, stream>>>(counts, offsets, cursor, C);
        scatter_kernel<<<dim3((B + 255) / 256), dim3(256), 0, stream>>>(labels, cursor, bkt, B);

        mb_class_kernel<<<dim3(C), dim3(256), 0, stream>>>(
            query, mkeys, mvals, qscores, topk, counts, offsets, bkt, out_ret, out_w);
    } else {
        mb_generic_kernel<<<dim3(B), dim3(64), 0, stream>>>(
            query, labels, mkeys, mvals, qscores, topk, out_ret, out_w, B, n4);
    }
}